// Round 9
// baseline (414.652 us; speedup 1.0000x reference)
//
#include <hip/hip_runtime.h>
#include <hip/hip_bf16.h>

// Problem constants
#define HH 256
#define WW 256
#define CCH 1024
#define PP 1024   // 32*32 patches per image

using f32x4 = __attribute__((ext_vector_type(4))) float;
using short8 = __attribute__((ext_vector_type(8))) short;

// ---------------------------------------------------------------------------
// Device bodies (proven in R5/R8), callable from mixed-grid kernels.
// ---------------------------------------------------------------------------
__device__ __forceinline__ void pool_body(const float* __restrict__ xb,
                                          float* __restrict__ yb, int c, int t) {
    int wid  = t >> 6;
    int lane = t & 63;
    const float* xp = xb + (size_t)c * (HH * WW) + lane * 4;
    float* yp = yb + (size_t)c * PP;
#pragma unroll
    for (int s = 0; s < 8; ++s) {
        int ph = wid + s * 4;
        const float* slab = xp + (size_t)ph * 8 * WW;
        float acc = 0.f;
#pragma unroll
        for (int r = 0; r < 8; ++r) {
            f32x4 v = *(const f32x4*)(slab + (size_t)r * WW);
            acc += v.x + v.y + v.z + v.w;
        }
        acc += __shfl_xor(acc, 1);
        if ((lane & 1) == 0)
            yp[ph * 32 + (lane >> 1)] = acc * (1.f / 64.f);
    }
}

__device__ __forceinline__ void apply_body(const float* __restrict__ xb,
                                           const float* __restrict__ gateb,
                                           float* __restrict__ outb,
                                           float* __restrict__ g,   // LDS, 1024 f32
                                           int c, int t) {
    const float* xp = xb   + (size_t)c * (HH * WW);
    float*       op = outb + (size_t)c * (HH * WW);
    ((f32x4*)g)[t] = ((const f32x4*)(gateb + (size_t)c * PP))[t];
    __syncthreads();
    int col4 = t & 63;
    int r    = t >> 6;
    int pc   = col4 >> 1;
#pragma unroll 4
    for (int it = 0; it < 64; ++it) {
        int row = it * 4 + r;
        float gg = g[(row >> 3) * 32 + pc];
        size_t off = (size_t)row * 64 + col4;
        f32x4 v = *((const f32x4*)xp + off);
        v *= gg;
        __builtin_nontemporal_store(v, (f32x4*)op + off);
    }
}

// ---------------------------------------------------------------------------
// L1: pool0 (blocks 0..1023) ∥ wconv+pad (blocks 1024..1279).
// wconv: f32 [co][ci][3] -> bf16 wT[tap][co][ci]; zero yT pad rows (both b).
// ---------------------------------------------------------------------------
__global__ __launch_bounds__(256) void pool0_wconv_kernel(
        const float* __restrict__ x, const float* __restrict__ w,
        float* __restrict__ y, __hip_bfloat16* __restrict__ wT,
        __hip_bfloat16* __restrict__ yT) {
    int bid = blockIdx.x, t = threadIdx.x;
    if (bid < 1024) {
        pool_body(x, y, bid, t);
    } else {
        int base = (bid - 1024) * 256 + t;       // 0..65535
#pragma unroll
        for (int it = 0; it < 16; ++it) {
            int idx = it * (1 << 16) + base;     // co*1024+ci
            const float* p = w + (size_t)idx * 3;
            wT[idx]               = __float2bfloat16(p[0]);
            wT[(1u << 20) + idx]  = __float2bfloat16(p[1]);
            wT[(2u << 20) + idx]  = __float2bfloat16(p[2]);
        }
        if (base < 2 * CCH) {
            int bb = base >> 10, cc = base & 1023;
            __hip_bfloat16 z = __float2bfloat16(0.f);
            __hip_bfloat16* basep = yT + (size_t)bb * (PP + 2) * CCH;
            basep[cc] = z;
            basep[(size_t)(PP + 1) * CCH + cc] = z;
        }
    }
}

// ---------------------------------------------------------------------------
// L4: apply0 reversed (blocks 0..1023, dispatched first -> reads x0 while L3
// warm) ∥ pool1 (blocks 1024..2047, streams x1 behind it).
// ---------------------------------------------------------------------------
__global__ __launch_bounds__(256) void apply0_pool1_kernel(
        const float* __restrict__ x, const float* __restrict__ gate,
        float* __restrict__ out, float* __restrict__ y) {
    __shared__ __align__(16) float g[PP];
    int bid = blockIdx.x, t = threadIdx.x;
    if (bid < 1024) {
        apply_body(x, gate, out, g, 1023 - bid, t);
    } else {
        const float* x1 = x + (size_t)CCH * HH * WW;
        float*       y1 = y + (size_t)CCH * PP;
        pool_body(x1, y1, bid - 1024, t);
    }
}

// ---------------------------------------------------------------------------
// apply-only kernel (L7): reversed planes.
// ---------------------------------------------------------------------------
__global__ __launch_bounds__(256) void apply_kernel(const float* __restrict__ xb,
                                                    const float* __restrict__ gateb,
                                                    float* __restrict__ outb) {
    __shared__ __align__(16) float g[PP];
    apply_body(xb, gateb, outb, g, 1023 - blockIdx.x, threadIdx.x);
}

// ---------------------------------------------------------------------------
// transpose (per batch): y[c][p] f32 -> yT[1+p][c] bf16, 32x32 LDS tiles.
// ---------------------------------------------------------------------------
__global__ __launch_bounds__(256) void transpose_kernel(const float* __restrict__ yb,
                                                        __hip_bfloat16* __restrict__ yTb) {
    int c0 = blockIdx.x * 32;
    int p0 = blockIdx.y * 32;
    __shared__ float tile[32][33];
    int tx = threadIdx.x, ty = threadIdx.y;    // 32 x 8
#pragma unroll
    for (int rr = 0; rr < 4; ++rr)
        tile[ty + rr * 8][tx] = yb[(size_t)(c0 + ty + rr * 8) * PP + p0 + tx];
    __syncthreads();
#pragma unroll
    for (int rr = 0; rr < 4; ++rr)
        yTb[(size_t)(1 + p0 + ty + rr * 8) * CCH + c0 + tx] =
            __float2bfloat16(tile[tx][ty + rr * 8]);
}

// ---------------------------------------------------------------------------
// gemm (per batch): R1-proven 256-thread body.  Block = 64(co) x 32(p),
// 4 waves stacked along co; wave tile 16x32.  Grid 16x32 = 512 blocks ->
// 2 blocks/CU, 8 waves/CU.
// ---------------------------------------------------------------------------
__global__ __launch_bounds__(256) void conv_gemm_kernel(
        const __hip_bfloat16* __restrict__ wT,
        const __hip_bfloat16* __restrict__ yTb,
        float* __restrict__ gateb) {
    int lane = threadIdx.x & 63;
    int wid  = threadIdx.x >> 6;
    int l15 = lane & 15, lhi = lane >> 4;
    int co_base = blockIdx.x * 64 + wid * 16;
    int p_base  = blockIdx.y * 32;
    f32x4 acc[2] = {};
#pragma unroll
    for (int tap = 0; tap < 3; ++tap) {
        const __hip_bfloat16* Ap = wT + (size_t)tap * (1u << 20)
                                 + (size_t)(co_base + l15) * CCH + lhi * 8;
        const __hip_bfloat16* Bp = yTb + (size_t)(p_base + l15 + tap) * CCH + lhi * 8;
        for (int ci0 = 0; ci0 < CCH; ci0 += 32) {
            short8 a0 = *(const short8*)(Ap + ci0);
            short8 b0 = *(const short8*)(Bp + ci0);
            short8 b1 = *(const short8*)(Bp + ci0 + 16 * CCH);
            acc[0] = __builtin_amdgcn_mfma_f32_16x16x32_bf16(a0, b0, acc[0], 0, 0, 0);
            acc[1] = __builtin_amdgcn_mfma_f32_16x16x32_bf16(a0, b1, acc[1], 0, 0, 0);
        }
    }
    // C/D layout: col = lane&15, row = (lane>>4)*4 + reg  [m89/m91].
#pragma unroll
    for (int j16 = 0; j16 < 2; ++j16) {
        int col  = p_base + j16 * 16 + l15;
        int row0 = co_base + lhi * 4;
#pragma unroll
        for (int r = 0; r < 4; ++r)
            gateb[(size_t)(row0 + r) * PP + col] = 1.f / (1.f + __expf(-acc[j16][r]));
    }
}

extern "C" void kernel_launch(void* const* d_in, const int* in_sizes, int n_in,
                              void* d_out, int out_size, void* d_ws, size_t ws_size,
                              hipStream_t stream) {
    const float* x = (const float*)d_in[0];       // [2,1024,256,256] f32
    const float* w = (const float*)d_in[1];       // [1024,1024,3] f32
    float* out = (float*)d_out;                   // [2,1024,256,256] f32

    // Workspace layout (256-aligned):
    //   y    f32  [2][1024][1024]   8,388,608 B @ 0
    //   yT   bf16 [2][1026][1024]   4,202,496 B @  8,388,608
    //   wT   bf16 [3][1024][1024]   6,291,456 B @ 12,591,104
    //   gate f32  [2][1024][1024]   8,388,608 B @ 18,882,560   (tot ~26 MiB)
    char* ws = (char*)d_ws;
    float*          y    = (float*)(ws);
    __hip_bfloat16* yT   = (__hip_bfloat16*)(ws + 8388608);
    __hip_bfloat16* wT   = (__hip_bfloat16*)(ws + 12591104);
    float*          gate = (float*)(ws + 18882560);

    const float* x1    = x    + (size_t)CCH * HH * WW;
    float*       y1    = y    + (size_t)CCH * PP;
    __hip_bfloat16* yT1 = yT  + (size_t)(PP + 2) * CCH;
    float*       gate1 = gate + (size_t)CCH * PP;
    float*       out1  = out  + (size_t)CCH * HH * WW;

    // L1: pool0 ∥ wconv+pad
    hipLaunchKernelGGL(pool0_wconv_kernel, dim3(1280), dim3(256), 0, stream,
                       x, w, y, wT, yT);
    // L2: transpose0
    hipLaunchKernelGGL(transpose_kernel, dim3(32, 32), dim3(32, 8), 0, stream, y, yT);
    // L3: gemm0 (x0 stays L3-warm; gemm churns only ~26 MB)
    hipLaunchKernelGGL(conv_gemm_kernel, dim3(16, 32), dim3(256), 0, stream, wT, yT, gate);
    // L4: apply0 (reversed, dispatched first) ∥ pool1
    hipLaunchKernelGGL(apply0_pool1_kernel, dim3(2048), dim3(256), 0, stream,
                       x, gate, out, y);
    // L5: transpose1
    hipLaunchKernelGGL(transpose_kernel, dim3(32, 32), dim3(32, 8), 0, stream, y1, yT1);
    // L6: gemm1
    hipLaunchKernelGGL(conv_gemm_kernel, dim3(16, 32), dim3(256), 0, stream, wT, yT1, gate1);
    // L7: apply1 (reversed)
    hipLaunchKernelGGL(apply_kernel, dim3(1024), dim3(256), 0, stream, x1, gate1, out1);
}

// Round 10
// 404.351 us; speedup vs baseline: 1.0255x; 1.0255x over previous
//
#include <hip/hip_runtime.h>
#include <hip/hip_bf16.h>

// Problem constants
#define HH 256
#define WW 256
#define CCH 1024
#define PP 1024   // 32*32 patches per image

using f32x4 = __attribute__((ext_vector_type(4))) float;
using short8 = __attribute__((ext_vector_type(8))) short;

// ---------------------------------------------------------------------------
// pool_direct: patch pool writing yT bf16 directly (no y, no transpose).
// job = ph*32 + cc: block computes patches (ph, pw=0..31) for 32 planes
// c = cc*32..cc*32+31, i.e. yT rows [1+ph*32 .. 1+ph*32+31], cols [c0,c0+32).
// Wave w reduces 8 planes (full 8x256 slab each, f32x4 NT row reads,
// shfl_xor(1) pair-reduce) -> LDS[pw][c_local]; writeback as short8 (16B),
// 64B cross-block granularity (R5-proven replay-safe).
// ---------------------------------------------------------------------------
__device__ __forceinline__ void pool_direct_body(const float* __restrict__ xb,
                                                 __hip_bfloat16* __restrict__ yTb,
                                                 int job, int t) {
    __shared__ float lds[32][33];
    int ph = job >> 5, c0 = (job & 31) * 32;
    int wid = t >> 6, lane = t & 63;
#pragma unroll 2
    for (int i = 0; i < 8; ++i) {
        int cl = wid * 8 + i;
        const float* base = xb + (size_t)(c0 + cl) * (HH * WW)
                          + (size_t)ph * 8 * WW + lane * 4;
        float acc = 0.f;
#pragma unroll
        for (int r = 0; r < 8; ++r) {
            f32x4 v = __builtin_nontemporal_load((const f32x4*)(base + r * WW));
            acc += v.x + v.y + v.z + v.w;
        }
        acc += __shfl_xor(acc, 1);
        if ((lane & 1) == 0)
            lds[lane >> 1][cl] = acc * (1.f / 64.f);
    }
    __syncthreads();
    if (t < 128) {
        int row = t >> 2, q = t & 3;
        short8 s;
#pragma unroll
        for (int j = 0; j < 8; ++j) {
            __hip_bfloat16 h = __float2bfloat16(lds[row][q * 8 + j]);
            s[j] = (short)reinterpret_cast<unsigned short&>(h);
        }
        *(short8*)(yTb + (size_t)(1 + ph * 32 + row) * CCH + c0 + q * 8) = s;
    }
}

// ---------------------------------------------------------------------------
// gemm body (R1/R9-proven): block = 64(co) x 32(p), 4 waves along co, wave
// tile 16x32.  job = by*16 + bx over grid 16x32.
// ---------------------------------------------------------------------------
__device__ __forceinline__ void gemm_body(const __hip_bfloat16* __restrict__ wT,
                                          const __hip_bfloat16* __restrict__ yTb,
                                          float* __restrict__ gateb,
                                          int job, int tid) {
    int lane = tid & 63;
    int wid  = tid >> 6;
    int l15 = lane & 15, lhi = lane >> 4;
    int co_base = (job & 15) * 64 + wid * 16;
    int p_base  = (job >> 4) * 32;
    f32x4 acc[2] = {};
#pragma unroll
    for (int tap = 0; tap < 3; ++tap) {
        const __hip_bfloat16* Ap = wT + (size_t)tap * (1u << 20)
                                 + (size_t)(co_base + l15) * CCH + lhi * 8;
        const __hip_bfloat16* Bp = yTb + (size_t)(p_base + l15 + tap) * CCH + lhi * 8;
        for (int ci0 = 0; ci0 < CCH; ci0 += 32) {
            short8 a0 = *(const short8*)(Ap + ci0);
            short8 b0 = *(const short8*)(Bp + ci0);
            short8 b1 = *(const short8*)(Bp + ci0 + 16 * CCH);
            acc[0] = __builtin_amdgcn_mfma_f32_16x16x32_bf16(a0, b0, acc[0], 0, 0, 0);
            acc[1] = __builtin_amdgcn_mfma_f32_16x16x32_bf16(a0, b1, acc[1], 0, 0, 0);
        }
    }
    // C/D layout: col = lane&15, row = (lane>>4)*4 + reg  [m89/m91].
#pragma unroll
    for (int j16 = 0; j16 < 2; ++j16) {
        int col  = p_base + j16 * 16 + l15;
        int row0 = co_base + lhi * 4;
#pragma unroll
        for (int r = 0; r < 4; ++r)
            gateb[(size_t)(row0 + r) * PP + col] = 1.f / (1.f + __expf(-acc[j16][r]));
    }
}

// ---------------------------------------------------------------------------
// apply body: gate row (4KB) in LDS; wave covers a full 256-col row per iter
// (f32x4 NT loads, NT stores).
// ---------------------------------------------------------------------------
__device__ __forceinline__ void apply_body(const float* __restrict__ xb,
                                           const float* __restrict__ gateb,
                                           float* __restrict__ outb,
                                           int c, int t) {
    __shared__ __align__(16) float g[PP];
    const float* xp = xb   + (size_t)c * (HH * WW);
    float*       op = outb + (size_t)c * (HH * WW);
    ((f32x4*)g)[t] = ((const f32x4*)(gateb + (size_t)c * PP))[t];
    __syncthreads();
    int col4 = t & 63;
    int r    = t >> 6;
    int pc   = col4 >> 1;
#pragma unroll 4
    for (int it = 0; it < 64; ++it) {
        int row = it * 4 + r;
        float gg = g[(row >> 3) * 32 + pc];
        size_t off = (size_t)row * 64 + col4;
        f32x4 v = __builtin_nontemporal_load((const f32x4*)xp + off);
        v *= gg;
        __builtin_nontemporal_store(v, (f32x4*)op + off);
    }
}

// ---------------------------------------------------------------------------
// L1: pool_direct(b0) [blocks 0..1023] ∥ wconv+pad [blocks 1024..1279].
// ---------------------------------------------------------------------------
__global__ __launch_bounds__(256) void pool0_wconv_kernel(
        const float* __restrict__ x, const float* __restrict__ w,
        __hip_bfloat16* __restrict__ yT, __hip_bfloat16* __restrict__ wT) {
    int bid = blockIdx.x, t = threadIdx.x;
    if (bid < 1024) {
        pool_direct_body(x, yT, bid, t);
    } else {
        int base = (bid - 1024) * 256 + t;       // 0..65535
#pragma unroll
        for (int it = 0; it < 16; ++it) {
            int idx = it * (1 << 16) + base;     // co*1024+ci
            const float* p = w + (size_t)idx * 3;
            wT[idx]               = __float2bfloat16(p[0]);
            wT[(1u << 20) + idx]  = __float2bfloat16(p[1]);
            wT[(2u << 20) + idx]  = __float2bfloat16(p[2]);
        }
        if (base < 2 * CCH) {
            int bb = base >> 10, cc = base & 1023;
            __hip_bfloat16 z = __float2bfloat16(0.f);
            __hip_bfloat16* basep = yT + (size_t)bb * (PP + 2) * CCH;
            basep[cc] = z;
            basep[(size_t)(PP + 1) * CCH + cc] = z;
        }
    }
}

// ---------------------------------------------------------------------------
// L2: gemm0 [blocks 0..511, starts immediately] ∥ pool_direct(b1) [512..1535].
// GEMM's ~35 µs of matrix/L2 work hides under pool1's HBM stream.
// ---------------------------------------------------------------------------
__global__ __launch_bounds__(256) void gemm0_pool1_kernel(
        const float* __restrict__ x, const __hip_bfloat16* __restrict__ wT,
        __hip_bfloat16* __restrict__ yT, float* __restrict__ gate) {
    int bid = blockIdx.x, t = threadIdx.x;
    if (bid < 512) {
        gemm_body(wT, yT, gate, bid, t);
    } else {
        const float* x1 = x + (size_t)CCH * HH * WW;
        __hip_bfloat16* yT1 = yT + (size_t)(PP + 2) * CCH;
        pool_direct_body(x1, yT1, bid - 512, t);
    }
}

// ---------------------------------------------------------------------------
// L3: gemm1 [blocks 0..511] ∥ apply0 [512..1535, reversed planes].
// ---------------------------------------------------------------------------
__global__ __launch_bounds__(256) void gemm1_apply0_kernel(
        const float* __restrict__ x, const __hip_bfloat16* __restrict__ wT,
        const __hip_bfloat16* __restrict__ yT, float* __restrict__ gate,
        float* __restrict__ out) {
    int bid = blockIdx.x, t = threadIdx.x;
    if (bid < 512) {
        const __hip_bfloat16* yT1 = yT + (size_t)(PP + 2) * CCH;
        float* gate1 = gate + (size_t)CCH * PP;
        gemm_body(wT, yT1, gate1, bid, t);
    } else {
        apply_body(x, gate, out, 1023 - (bid - 512), t);
    }
}

// ---------------------------------------------------------------------------
// L4: apply1 (reversed planes).
// ---------------------------------------------------------------------------
__global__ __launch_bounds__(256) void apply1_kernel(
        const float* __restrict__ x, const float* __restrict__ gate,
        float* __restrict__ out) {
    const float* x1    = x    + (size_t)CCH * HH * WW;
    const float* gate1 = gate + (size_t)CCH * PP;
    float*       out1  = out  + (size_t)CCH * HH * WW;
    apply_body(x1, gate1, out1, 1023 - blockIdx.x, threadIdx.x);
}

extern "C" void kernel_launch(void* const* d_in, const int* in_sizes, int n_in,
                              void* d_out, int out_size, void* d_ws, size_t ws_size,
                              hipStream_t stream) {
    const float* x = (const float*)d_in[0];       // [2,1024,256,256] f32
    const float* w = (const float*)d_in[1];       // [1024,1024,3] f32
    float* out = (float*)d_out;                   // [2,1024,256,256] f32

    // Workspace layout (256-aligned):
    //   yT   bf16 [2][1026][1024]   4,202,496 B @ 0
    //   wT   bf16 [3][1024][1024]   6,291,456 B @  4,202,496
    //   gate f32  [2][1024][1024]   8,388,608 B @ 10,493,952   (tot ~18.9 MiB)
    char* ws = (char*)d_ws;
    __hip_bfloat16* yT   = (__hip_bfloat16*)(ws);
    __hip_bfloat16* wT   = (__hip_bfloat16*)(ws + 4202496);
    float*          gate = (float*)(ws + 10493952);

    hipLaunchKernelGGL(pool0_wconv_kernel, dim3(1280), dim3(256), 0, stream,
                       x, w, yT, wT);
    hipLaunchKernelGGL(gemm0_pool1_kernel, dim3(1536), dim3(256), 0, stream,
                       x, wT, yT, gate);
    hipLaunchKernelGGL(gemm1_apply0_kernel, dim3(1536), dim3(256), 0, stream,
                       x, wT, yT, gate, out);
    hipLaunchKernelGGL(apply1_kernel, dim3(1024), dim3(256), 0, stream,
                       x, gate, out);
}